// Round 7
// baseline (936.448 us; speedup 1.0000x reference)
//
#include <hip/hip_runtime.h>
#include <math.h>

// FAVOR+ linear attention, B=4 S=4096 D=1024 H=16 DH=64 M=128.
// Wire dtype (fp32 vs bf16) detected at runtime from pos_ft_scale (== 1.0):
//   word0 == 0x3F800000 -> fp32 wire; 0x3F803F80 -> bf16 wire.
//
// Round-7: coalesced epilogues for featurize/av (LDS bounce, uint4 stores);
// prologue staging merged into one launch. gemm_mega (at m97-structure
// ceiling, 923 TF eff) and the rest unchanged from round 6.
//
// ws map: 0 wvt(2M) | 2M wot(2M) | 4M W2(4M) | 8M nrm(256K) | +256K P2(64K)
//  | +320K kvsTh(512K) | +832K kvsTl(512K) | 10M posp f32(16M) | 26M slpp(16M)
//  | 42M valb/av(8M) | 50M vT(8M) | 58M dyn: qp(2G MiB) kpT(2G MiB).
//  A2(32M) aliases qp+; srcb(8M) aliases kpT start (G=16 path).
//  kvp(16M) aliases posp after featurize.

typedef unsigned short u16;
typedef __attribute__((ext_vector_type(8))) short bf16x8;
typedef __attribute__((ext_vector_type(4))) float floatx4;

__device__ __forceinline__ float bf2f(u16 u) {
  union { unsigned int i; float f; } v; v.i = ((unsigned int)u) << 16; return v.f;
}
__device__ __forceinline__ u16 f2bf(float f) {
  union { float f; unsigned int i; } v; v.f = f;
  unsigned int r = v.i + 0x7fffu + ((v.i >> 16) & 1u);
  return (u16)(r >> 16);
}
__device__ __forceinline__ bool wire_f32(const unsigned* probe) {
  return probe[0] == 0x3F800000u;
}
__device__ __forceinline__ void gload_lds16(const void* g, void* l) {
  __builtin_amdgcn_global_load_lds(
      (const __attribute__((address_space(1))) void*)g,
      (__attribute__((address_space(3))) void*)l, 16, 0, 0);
}

// ---------------------------------------------------------------------------
// Shared m97-style GEMM body (used by gemm_gl and mega2's gemm part).
// ---------------------------------------------------------------------------
__device__ __forceinline__ void gemm_body(
    const u16* __restrict__ A, int lda, const u16* __restrict__ B, int ldb,
    void* __restrict__ C, long coff, int Klog, int fold, int ofmt, bool f32w,
    long m0, long n0, u16* sA, u16* sB)
{
  const int t = threadIdx.x;
  const int wave = t >> 6, lane = t & 63;
  const int ll = lane & 15, quad = lane >> 4;
  const int wm0 = (wave >> 1) * 64, wn0 = (wave & 1) * 64;
  const int lr = lane >> 2, lc = (lane & 3) * 8;
  floatx4 acc[4][4];
  floatx4 zero = {0.0f, 0.0f, 0.0f, 0.0f};
  #pragma unroll
  for (int i = 0; i < 4; i++)
    #pragma unroll
    for (int j = 0; j < 4; j++) acc[i][j] = zero;

  for (int kc = 0; kc < Klog; kc += 32) {
    int akc = kc, bkc = kc;
    if (fold) {
      akc = (kc < 1024) ? kc : kc - 1024;
      bkc = (kc < 2048) ? kc : kc - 2048;
    }
    #pragma unroll
    for (int j = 0; j < 2; j++) {
      int r0 = wave * 32 + j * 16;
      gload_lds16(&A[(m0 + r0 + lr) * (long)lda + akc + lc], &sA[r0 * 32]);
      gload_lds16(&B[(n0 + r0 + lr) * (long)ldb + bkc + lc], &sB[r0 * 32]);
    }
    __syncthreads();
    bf16x8 af[4], bfr[4];
    #pragma unroll
    for (int i = 0; i < 4; i++) {
      af[i]  = *(const bf16x8*)&sA[(wm0 + i * 16 + ll) * 32 + quad * 8];
      bfr[i] = *(const bf16x8*)&sB[(wn0 + i * 16 + ll) * 32 + quad * 8];
    }
    #pragma unroll
    for (int i = 0; i < 4; i++)
      #pragma unroll
      for (int j = 0; j < 4; j++)
        acc[i][j] = __builtin_amdgcn_mfma_f32_16x16x32_bf16(af[i], bfr[j], acc[i][j], 0, 0, 0);
    __syncthreads();
  }
  #pragma unroll
  for (int i = 0; i < 4; i++)
    #pragma unroll
    for (int j = 0; j < 4; j++)
      #pragma unroll
      for (int r = 0; r < 4; r++) {
        long row = m0 + wm0 + i * 16 + quad * 4 + r;
        long col = n0 + wn0 + j * 16 + ll;
        float v = acc[i][j][r];
        long addr = coff + row * 1024 + col;
        if (ofmt == 0) ((u16*)C)[addr] = f2bf(v);
        else if (ofmt == 1) ((float*)C)[addr] = v;
        else if (f32w) ((float*)C)[addr] = v;
        else ((u16*)C)[addr] = f2bf(v);
      }
}

// Standalone GEMM (fallback paths + final output GEMM).
__global__ __launch_bounds__(256) void gemm_gl(
    const u16* __restrict__ A, int lda, const u16* __restrict__ B, int ldb,
    void* __restrict__ C, long coff, int Klog, int fold, int ofmt,
    const unsigned* __restrict__ probe)
{
  __shared__ u16 sA[128 * 32], sB[128 * 32];
  gemm_body(A, lda, B, ldb, C, coff, Klog, fold, ofmt, wire_f32(probe),
            (long)blockIdx.x * 128, (long)blockIdx.y * 128, sA, sB);
}

// ---------------------------------------------------------------------------
// Mega GEMM: 768 blocks, XCD-chunked decode (xcd = id&7).
// ---------------------------------------------------------------------------
__global__ __launch_bounds__(256) void gemm_mega(
    const u16* __restrict__ A2, const u16* __restrict__ W2,
    float* __restrict__ posp, const u16* __restrict__ srcb,
    const u16* __restrict__ wvt, u16* __restrict__ vT,
    const unsigned* __restrict__ probe)
{
  __shared__ u16 pool[20480];  // 40 KiB
  const int id = blockIdx.x;
  const int xcd = id & 7, pos = id >> 3;
  const int t = threadIdx.x;
  const int wave = t >> 6, lane = t & 63;
  const int ll = lane & 15, quad = lane >> 4;
  const int wm0 = (wave >> 1) * 64, wn0 = (wave & 1) * 64;
  const int lr = lane >> 2, lc = (lane & 3) * 8;
  floatx4 acc[4][4];
  floatx4 zero = {0.0f, 0.0f, 0.0f, 0.0f};
  #pragma unroll
  for (int i = 0; i < 4; i++)
    #pragma unroll
    for (int j = 0; j < 4; j++) acc[i][j] = zero;

  if (pos < 64) {
    // ---- projection fold GEMM, interleaved hi/lo staging ----
    int tile = xcd * 64 + pos;
    long m0 = (long)(tile >> 3) * 128, n0 = (long)(tile & 7) * 128;
    u16* sAh = pool;
    u16* sAl = pool + 4096;
    u16* sBh = pool + 8192;
    u16* sBl = pool + 12288;
    for (int kc = 0; kc < 1024; kc += 32) {
      #pragma unroll
      for (int j = 0; j < 2; j++) {
        int r0 = wave * 32 + j * 16;
        gload_lds16(&A2[(m0 + r0 + lr) * 2048 + kc + lc],        &sAh[r0 * 32]);
        gload_lds16(&A2[(m0 + r0 + lr) * 2048 + 1024 + kc + lc], &sAl[r0 * 32]);
        gload_lds16(&W2[(n0 + r0 + lr) * 2048 + kc + lc],        &sBh[r0 * 32]);
        gload_lds16(&W2[(n0 + r0 + lr) * 2048 + 1024 + kc + lc], &sBl[r0 * 32]);
      }
      __syncthreads();
      bf16x8 ah[4], al[4], bh[4], bl[4];
      #pragma unroll
      for (int i = 0; i < 4; i++) {
        ah[i] = *(const bf16x8*)&sAh[(wm0 + i * 16 + ll) * 32 + quad * 8];
        al[i] = *(const bf16x8*)&sAl[(wm0 + i * 16 + ll) * 32 + quad * 8];
        bh[i] = *(const bf16x8*)&sBh[(wn0 + i * 16 + ll) * 32 + quad * 8];
        bl[i] = *(const bf16x8*)&sBl[(wn0 + i * 16 + ll) * 32 + quad * 8];
      }
      #pragma unroll
      for (int i = 0; i < 4; i++)
        #pragma unroll
        for (int j = 0; j < 4; j++) {
          acc[i][j] = __builtin_amdgcn_mfma_f32_16x16x32_bf16(ah[i], bh[j], acc[i][j], 0, 0, 0);
          acc[i][j] = __builtin_amdgcn_mfma_f32_16x16x32_bf16(ah[i], bl[j], acc[i][j], 0, 0, 0);
          acc[i][j] = __builtin_amdgcn_mfma_f32_16x16x32_bf16(al[i], bh[j], acc[i][j], 0, 0, 0);
        }
      __syncthreads();
    }
    #pragma unroll
    for (int i = 0; i < 4; i++)
      #pragma unroll
      for (int j = 0; j < 4; j++)
        #pragma unroll
        for (int r = 0; r < 4; r++) {
          long row = m0 + wm0 + i * 16 + quad * 4 + r;
          long col = n0 + wn0 + j * 16 + ll;
          posp[row * 1024 + col] = acc[i][j][r];
        }
  } else {
    // ---- value GEMM with fused transposed output ----
    int v = xcd * 32 + (pos - 64);
    long m0 = (long)(v >> 3) * 128, n0 = (long)(v & 7) * 128;
    u16* sA = pool;
    u16* sB = pool + 4096;
    for (int kc = 0; kc < 1024; kc += 32) {
      #pragma unroll
      for (int j = 0; j < 2; j++) {
        int r0 = wave * 32 + j * 16;
        gload_lds16(&srcb[(m0 + r0 + lr) * 1024 + kc + lc], &sA[r0 * 32]);
        gload_lds16(&wvt[(n0 + r0 + lr) * 1024 + kc + lc],  &sB[r0 * 32]);
      }
      __syncthreads();
      bf16x8 af[4], bfr[4];
      #pragma unroll
      for (int i = 0; i < 4; i++) {
        af[i]  = *(const bf16x8*)&sA[(wm0 + i * 16 + ll) * 32 + quad * 8];
        bfr[i] = *(const bf16x8*)&sB[(wn0 + i * 16 + ll) * 32 + quad * 8];
      }
      #pragma unroll
      for (int i = 0; i < 4; i++)
        #pragma unroll
        for (int j = 0; j < 4; j++)
          acc[i][j] = __builtin_amdgcn_mfma_f32_16x16x32_bf16(af[i], bfr[j], acc[i][j], 0, 0, 0);
      __syncthreads();
    }
    // LDS-bounce transpose: sT[d][l].
    u16 (*sT)[136] = (u16(*)[136])pool;
    #pragma unroll
    for (int i = 0; i < 4; i++)
      #pragma unroll
      for (int j = 0; j < 4; j++)
        #pragma unroll
        for (int r = 0; r < 4; r++)
          sT[wn0 + j * 16 + ll][wm0 + i * 16 + quad * 4 + r] = f2bf(acc[i][j][r]);
    __syncthreads();
    for (int u = t; u < 2048; u += 256) {
      int d = u >> 4, c8 = (u & 15) * 8;
      *(uint4*)&vT[(n0 + d) * 4096 + m0 + c8] = *(const uint4*)&sT[d][c8];
    }
  }
}

// ---------------------------------------------------------------------------
// Elementwise bodies.
// ---------------------------------------------------------------------------
__device__ __forceinline__ void split_body(
    const void* __restrict__ Aw, long aoff, u16* __restrict__ A2, int rowbase,
    bool f32w, long idx)
{
  int row = (int)(idx >> 7);
  int c8 = (int)(idx & 127) * 8;
  u16 h8[8], l8[8];
  if (f32w) {
    const float* ap = (const float*)Aw + aoff + (long)row * 1024 + c8;
    #pragma unroll
    for (int e = 0; e < 8; e++) {
      float v = ap[e]; u16 hb = f2bf(v);
      h8[e] = hb; l8[e] = f2bf(v - bf2f(hb));
    }
  } else {
    *(uint4*)h8 = *(const uint4*)((const u16*)Aw + aoff + (long)row * 1024 + c8);
    #pragma unroll
    for (int e = 0; e < 8; e++) l8[e] = 0;
  }
  u16* orow = A2 + (long)(rowbase + row) * 2048;
  *(uint4*)&orow[c8] = *(uint4*)h8;
  *(uint4*)&orow[1024 + c8] = *(uint4*)l8;
}

__device__ __forceinline__ void conv_body(
    const void* __restrict__ Aw, long aoff, u16* __restrict__ out,
    bool f32w, long idx)
{
  long base = idx * 8;
  u16 h8[8];
  if (f32w) {
    const float* ap = (const float*)Aw + aoff + base;
    #pragma unroll
    for (int e = 0; e < 8; e++) h8[e] = f2bf(ap[e]);
  } else {
    *(uint4*)h8 = *(const uint4*)((const u16*)Aw + aoff + base);
  }
  *(uint4*)&out[base] = *(uint4*)h8;
}

__global__ __launch_bounds__(256) void split_hilo(
    const void* __restrict__ Aw, long aoff, u16* __restrict__ A2, int rowbase,
    const unsigned* __restrict__ probe)
{
  split_body(Aw, aoff, A2, rowbase, wire_f32(probe),
             (long)blockIdx.x * 256 + threadIdx.x);
}

__global__ __launch_bounds__(256) void conv_bf16(
    const void* __restrict__ Aw, long aoff, u16* __restrict__ out,
    const unsigned* __restrict__ probe)
{
  conv_body(Aw, aoff, out, wire_f32(probe),
            (long)blockIdx.x * 256 + threadIdx.x);
}

// stage3: 6144 blocks. 0..2047 split pos; 2048..4095 split slp; 4096+ conv src.
__global__ __launch_bounds__(256) void stage3(
    const void* __restrict__ posf, const void* __restrict__ slpf,
    const void* __restrict__ src, long ioff,
    u16* __restrict__ A2, u16* __restrict__ srcb,
    const unsigned* __restrict__ probe)
{
  const bool f32w = wire_f32(probe);
  int id = blockIdx.x;
  if (id < 2048)
    split_body(posf, ioff, A2, 0, f32w, (long)id * 256 + threadIdx.x);
  else if (id < 4096)
    split_body(slpf, ioff, A2, 4096, f32w, (long)(id - 2048) * 256 + threadIdx.x);
  else
    conv_body(src, ioff, srcb, f32w, (long)(id - 4096) * 256 + threadIdx.x);
}

// Mega 2: blocks 0..255 output GEMM of batch b; rest = staging of b+1.
__global__ __launch_bounds__(256) void mega2(
    const u16* __restrict__ av, const u16* __restrict__ wot,
    void* __restrict__ dout, long coff,
    const void* __restrict__ posf, const void* __restrict__ slpf,
    const void* __restrict__ src, long ioff_next,
    u16* __restrict__ A2, u16* __restrict__ srcb,
    const unsigned* __restrict__ probe)
{
  __shared__ u16 sA[128 * 32], sB[128 * 32];
  const bool f32w = wire_f32(probe);
  int id = blockIdx.x;
  if (id < 256) {
    int tile = (id & 7) * 32 + (id >> 3);
    gemm_body(av, 1024, wot, 1024, dout, coff, 1024, 0, 2, f32w,
              (long)(tile >> 3) * 128, (long)(tile & 7) * 128, sA, sB);
  } else if (id < 2304) {
    split_body(posf, ioff_next, A2, 0, f32w,
               (long)(id - 256) * 256 + threadIdx.x);
  } else if (id < 4352) {
    split_body(slpf, ioff_next, A2, 4096, f32w,
               (long)(id - 2304) * 256 + threadIdx.x);
  } else {
    conv_body(src, ioff_next, srcb, f32w,
              (long)(id - 4352) * 256 + threadIdx.x);
  }
}

// ---------------------------------------------------------------------------
// Weight transposes.
// ---------------------------------------------------------------------------
__global__ __launch_bounds__(256) void transpose_w(
    const void* __restrict__ in, u16* __restrict__ outb,
    const unsigned* __restrict__ probe)
{
  __shared__ float s[64][65];
  const bool f32w = wire_f32(probe);
  int t = threadIdx.x;
  int r0 = blockIdx.y * 64, c0 = blockIdx.x * 64;
  for (int u = t; u < 4096; u += 256) {
    int r = u >> 6, c = u & 63;
    long idx = (long)(r0 + r) * 1024 + c0 + c;
    s[c][r] = f32w ? ((const float*)in)[idx] : bf2f(((const u16*)in)[idx]);
  }
  __syncthreads();
  for (int u = t; u < 4096; u += 256) {
    int r = u >> 6, c = u & 63;
    outb[(long)(c0 + r) * 1024 + r0 + c] = f2bf(s[r][c]);
  }
}

__global__ __launch_bounds__(256) void transpose_w2(
    const void* __restrict__ in, u16* __restrict__ out2,
    const unsigned* __restrict__ probe)
{
  __shared__ float s[64][65];
  const bool f32w = wire_f32(probe);
  int t = threadIdx.x;
  int r0 = blockIdx.y * 64, c0 = blockIdx.x * 64;
  for (int u = t; u < 4096; u += 256) {
    int r = u >> 6, c = u & 63;
    long idx = (long)(r0 + r) * 1024 + c0 + c;
    s[c][r] = f32w ? ((const float*)in)[idx] : bf2f(((const u16*)in)[idx]);
  }
  __syncthreads();
  for (int u = t; u < 4096; u += 256) {
    int r = u >> 6, c = u & 63;
    float v = s[r][c];
    u16 hb = f2bf(v);
    long rowb = (long)(c0 + r) * 2048;
    out2[rowb + r0 + c] = hb;
    out2[rowb + 1024 + r0 + c] = f2bf(v - bf2f(hb));
  }
}

// proj_prep: P2[m][0:64]=hi(dn*proj[m][d]), [64:128]=lo.
__global__ __launch_bounds__(256) void proj_prep(
    const void* __restrict__ proj, u16* __restrict__ P2,
    const unsigned* __restrict__ probe)
{
  const bool f32w = wire_f32(probe);
  int idx = blockIdx.x * 256 + threadIdx.x;  // 8192
  int m = idx >> 6, d = idx & 63;
  const float dn = 0.3535533905932738f;      // 64^-0.25
  float v = dn * (f32w ? ((const float*)proj)[idx] : bf2f(((const u16*)proj)[idx]));
  u16 hb = f2bf(v);
  P2[(long)m * 128 + d] = hb;
  P2[(long)m * 128 + 64 + d] = f2bf(v - bf2f(hb));
}

// ---------------------------------------------------------------------------
// featurize_mfma: grid (64, G), block 256 (4 waves, 2Mx2N).
// Round-7: LDS-bounce epilogue -> all qp/kpT stores are coalesced uint4.
// Pool: staging sAp/sAs/sB (64 KiB) reused by sq[64][264] + sk[256][72].
// ---------------------------------------------------------------------------
__global__ __launch_bounds__(256) void featurize_mfma(
    const float* __restrict__ posp, const float* __restrict__ slpp,
    const u16* __restrict__ P2, const void* __restrict__ scl,
    const void* __restrict__ offs, u16* __restrict__ qp, u16* __restrict__ kpT,
    const unsigned* __restrict__ probe, int h0)
{
  __shared__ u16 pool[35328];  // 69 KiB
  u16* sAp = pool;             // 4*64*32
  u16* sAs = pool + 8192;      // 4*64*32
  u16* sB  = pool + 16384;     // 4*128*32
  const bool f32w = wire_f32(probe);
  const int t = threadIdx.x;
  const int wave = t >> 6, lane = t & 63;
  const int ll = lane & 15, quad = lane >> 4;
  const int wm0 = (wave >> 1) * 32, wn0 = (wave & 1) * 64;
  const int g = blockIdx.y, h = h0 + g;
  const int l0 = blockIdx.x * 64;
  const float s1 = f32w ? ((const float*)scl)[h] : bf2f(((const u16*)scl)[h]);
  const float s2 = (f32w ? ((const float*)offs)[h] : bf2f(((const u16*)offs)[h])) * s1;
  const float ratio = 0.08838834764831845f;  // 128^-0.5

  for (int u = t; u < 512; u += 256) {
    int r = u >> 3, cc = u & 7;
    const float* pp = posp + (long)(l0 + r) * 1024 + h * 64 + cc * 8;
    const float* sp = slpp + (long)(l0 + r) * 1024 + h * 64 + cc * 8;
    u16 ph[8], pl[8], sh[8], sl[8];
    #pragma unroll
    for (int e = 0; e < 8; e++) {
      float vp = pp[e]; u16 hb = f2bf(vp);
      ph[e] = hb; pl[e] = f2bf(vp - bf2f(hb));
      float vs = sp[e]; u16 sb = f2bf(vs);
      sh[e] = sb; sl[e] = f2bf(vs - bf2f(sb));
    }
    int ch = cc >> 2, cw = (cc & 3) * 8;
    *(uint4*)&sAp[((ch) * 64 + r) * 32 + cw]     = *(uint4*)ph;
    *(uint4*)&sAp[((2 + ch) * 64 + r) * 32 + cw] = *(uint4*)pl;
    *(uint4*)&sAs[((ch) * 64 + r) * 32 + cw]     = *(uint4*)sh;
    *(uint4*)&sAs[((2 + ch) * 64 + r) * 32 + cw] = *(uint4*)sl;
  }
  for (int u = t; u < 2048; u += 256) {
    int r = u >> 4, q4 = u & 15;
    uint4 v = *(const uint4*)&P2[(long)r * 128 + q4 * 8];
    int ch = q4 >> 2, cw = (q4 & 3) * 8;
    *(uint4*)&sB[(ch * 128 + r) * 32 + cw] = v;
  }
  __syncthreads();

  floatx4 accp[2][4], accs[2][4];
  floatx4 zero = {0.0f, 0.0f, 0.0f, 0.0f};
  #pragma unroll
  for (int i = 0; i < 2; i++)
    #pragma unroll
    for (int j = 0; j < 4; j++) { accp[i][j] = zero; accs[i][j] = zero; }

  const int ACH[6] = {0, 1, 0, 1, 2, 3};
  const int BCH[6] = {0, 1, 2, 3, 0, 1};
  #pragma unroll
  for (int kci = 0; kci < 6; kci++) {
    int ac = ACH[kci], bc = BCH[kci];
    bf16x8 ap[2], as2[2], bfr[4];
    #pragma unroll
    for (int i = 0; i < 2; i++) {
      ap[i]  = *(const bf16x8*)&sAp[(ac * 64 + wm0 + i * 16 + ll) * 32 + quad * 8];
      as2[i] = *(const bf16x8*)&sAs[(ac * 64 + wm0 + i * 16 + ll) * 32 + quad * 8];
    }
    #pragma unroll
    for (int j = 0; j < 4; j++)
      bfr[j] = *(const bf16x8*)&sB[(bc * 128 + wn0 + j * 16 + ll) * 32 + quad * 8];
    #pragma unroll
    for (int i = 0; i < 2; i++)
      #pragma unroll
      for (int j = 0; j < 4; j++) {
        accp[i][j] = __builtin_amdgcn_mfma_f32_16x16x32_bf16(ap[i],  bfr[j], accp[i][j], 0, 0, 0);
        accs[i][j] = __builtin_amdgcn_mfma_f32_16x16x32_bf16(as2[i], bfr[j], accs[i][j], 0, 0, 0);
      }
  }

  // Epilogue: sin/cos -> LDS tiles -> coalesced uint4 stores.
  u16* sq = pool;              // [64][264]
  u16* sk = pool + 64 * 264;   // [256][72]
  __syncthreads();             // staging LDS dead; reuse pool
  #pragma unroll
  for (int i = 0; i < 2; i++) {
    int lrow = wm0 + i * 16 + quad * 4;
    #pragma unroll
    for (int j = 0; j < 4; j++) {
      int m = wn0 + j * 16 + ll;
      #pragma unroll
      for (int r = 0; r < 4; r++) {
        float dq = s1 * accp[i][j][r];
        float dk = dq + s2 * accs[i][j][r];
        dq = fminf(fmaxf(dq, -10000.0f), 10000.0f);
        dk = fminf(fmaxf(dk, -10000.0f), 10000.0f);
        sq[(lrow + r) * 264 + m]       = f2bf(ratio * __sinf(dq));
        sq[(lrow + r) * 264 + 128 + m] = f2bf(ratio * __cosf(dq));
        sk[m * 72 + lrow + r]          = f2bf(ratio * __sinf(dk));
        sk[(m + 128) * 72 + lrow + r]  = f2bf(ratio * __cosf(dk));
      }
    }
  }
  __syncthreads();
  for (int u = t; u < 2048; u += 256) {
    int rrow = u >> 5, c8 = (u & 31) * 8;
    *(uint4*)&qp[((long)g * 4096 + l0 + rrow) * 256 + c8] =
        *(const uint4*)&sq[rrow * 264 + c8];
  }
  for (int u = t; u < 2048; u += 256) {
    int mrow = u >> 3, c8 = (u & 7) * 8;
    *(uint4*)&kpT[((long)(g * 256 + mrow)) * 4096 + l0 + c8] =
        *(const uint4*)&sk[mrow * 72 + c8];
  }
}

// ---------------------------------------------------------------------------
// Value transpose (fallback G<16 path only).
// ---------------------------------------------------------------------------
__global__ __launch_bounds__(256) void transpose_v(
    const u16* __restrict__ in, u16* __restrict__ out)
{
  __shared__ u16 s[64][72];
  int t = threadIdx.x;
  int c0 = blockIdx.x * 64;
  int r0 = blockIdx.y * 64;
  for (int u = t; u < 512; u += 256) {
    int r = u >> 3, c8 = (u & 7) * 8;
    uint4 v = *(const uint4*)&in[(long)(r0 + r) * 1024 + c0 + c8];
    const u16* pv = (const u16*)&v;
    #pragma unroll
    for (int e = 0; e < 8; e++) s[c8 + e][r] = pv[e];
  }
  __syncthreads();
  for (int u = t; u < 512; u += 256) {
    int r = u >> 3, c8 = (u & 7) * 8;
    *(uint4*)&out[(long)(c0 + r) * 4096 + r0 + c8] = *(const uint4*)&s[r][c8];
  }
}

// nrm[l*16+h] = ||slpp[l, h*64 .. +64)|| / 4096
__global__ __launch_bounds__(256) void norm_kernel(
    const float* __restrict__ slp, float* __restrict__ nrm)
{
  int idx = blockIdx.x * 256 + threadIdx.x;  // 65536
  int row = idx >> 4, h = idx & 15;
  const float* p = slp + (long)row * 1024 + h * 64;
  float acc = 0.0f;
  #pragma unroll
  for (int i = 0; i < 16; i++) {
    float4 v = *(const float4*)&p[i * 4];
    acc += v.x * v.x + v.y * v.y + v.z * v.z + v.w * v.w;
  }
  nrm[idx] = sqrtf(acc) * (1.0f / 4096.0f);
}

// ---------------------------------------------------------------------------
// kvs partial GEMM (MFMA): grid (KS, G), block 256 (4 waves).
// ---------------------------------------------------------------------------
__global__ __launch_bounds__(256) void kvs_mfma(
    const u16* __restrict__ kpT, const u16* __restrict__ vT,
    float* __restrict__ kvp, int h0)
{
  __shared__ u16 sA[256][40], sB[64][40];
  const int t = threadIdx.x;
  const int wave = t >> 6, lane = t & 63;
  const int ll = lane & 15, quad = lane >> 4;
  const int wm0 = wave * 64;
  const int ks = blockIdx.x, g = blockIdx.y;
  const int G = gridDim.y, KS = gridDim.x;
  const int h = h0 + g;
  const int lch = 4096 / KS;
  const int lbase = ks * lch;
  floatx4 acc[4][4];
  floatx4 zero = {0.0f, 0.0f, 0.0f, 0.0f};
  #pragma unroll
  for (int i = 0; i < 4; i++)
    #pragma unroll
    for (int j = 0; j < 4; j++) acc[i][j] = zero;

  for (int kc = 0; kc < lch; kc += 32) {
    for (int u = t; u < 1024; u += 256) {
      int r = u >> 2, s = u & 3;
      *(uint4*)&sA[r][s * 8] =
          *(const uint4*)&kpT[((long)(g * 256 + r)) * 4096 + lbase + kc + s * 8];
    }
    {
      int r = t >> 2, s = t & 3;
      if (t < 256)
        *(uint4*)&sB[r][s * 8] =
            *(const uint4*)&vT[((long)(h * 64 + r)) * 4096 + lbase + kc + s * 8];
    }
    __syncthreads();
    bf16x8 af[4], bfr[4];
    #pragma unroll
    for (int i = 0; i < 4; i++) {
      af[i] = *(const bf16x8*)&sA[wm0 + i * 16 + ll][quad * 8];
      bfr[i] = *(const bf16x8*)&sB[i * 16 + ll][quad * 8];
    }
    #pragma unroll
    for (int i = 0; i < 4; i++)
      #pragma unroll
      for (int j = 0; j < 4; j++)
        acc[i][j] = __builtin_amdgcn_mfma_f32_16x16x32_bf16(af[i], bfr[j], acc[i][j], 0, 0, 0);
    __syncthreads();
  }
  long obase = ((long)ks * G + g) * 256;
  #pragma unroll
  for (int i = 0; i < 4; i++)
    #pragma unroll
    for (int j = 0; j < 4; j++)
      #pragma unroll
      for (int r = 0; r < 4; r++) {
        int row = wm0 + i * 16 + quad * 4 + r;
        int col = j * 16 + ll;
        kvp[(obase + row) * 64 + col] = acc[i][j][r];
      }
}

// ---------------------------------------------------------------------------
// Reduce partials, transpose, pre-split hi/lo.
// ---------------------------------------------------------------------------
__global__ __launch_bounds__(256) void kvs_reduce(
    const float* __restrict__ kvp, u16* __restrict__ kvsTh,
    u16* __restrict__ kvsTl, int G, int KS)
{
  int idx = blockIdx.x * 256 + threadIdx.x;  // G*64*256
  int m = idx & 255, d = (idx >> 8) & 63, g = idx >> 14;
  float s = 0.0f;
  for (int p = 0; p < KS; p++)
    s += kvp[(((long)p * G + g) * 256 + m) * 64 + d];
  u16 hb = f2bf(s);
  long o = ((long)g * 64 + d) * 256 + m;
  kvsTh[o] = hb;
  kvsTl[o] = f2bf(s - bf2f(hb));
}

// ---------------------------------------------------------------------------
// av GEMM (MFMA): grid (32, G), block 256. Round-7: LDS-bounce epilogue.
// ---------------------------------------------------------------------------
__global__ __launch_bounds__(256) void av_mfma(
    const u16* __restrict__ qp, const u16* __restrict__ kvsTh,
    const u16* __restrict__ kvsTl, const float* __restrict__ nrm,
    u16* __restrict__ av, int h0)
{
  __shared__ u16 pool[10240];  // 20 KiB: sA 5120 | sBh 2560 | sBl 2560
  u16* sA  = pool;
  u16* sBh = pool + 5120;
  u16* sBl = pool + 7680;
  const int t = threadIdx.x;
  const int wave = t >> 6, lane = t & 63;
  const int ll = lane & 15, quad = lane >> 4;
  const int wm0 = wave * 32;
  const int g = blockIdx.y, h = h0 + g;
  const int l0 = blockIdx.x * 128;
  floatx4 acc[2][4];
  floatx4 zero = {0.0f, 0.0f, 0.0f, 0.0f};
  #pragma unroll
  for (int i = 0; i < 2; i++)
    #pragma unroll
    for (int j = 0; j < 4; j++) acc[i][j] = zero;

  for (int kc = 0; kc < 256; kc += 32) {
    for (int u = t; u < 512; u += 256) {
      int r = u >> 2, s = u & 3;
      *(uint4*)&sA[r * 40 + s * 8] =
          *(const uint4*)&qp[((long)g * 4096 + l0 + r) * 256 + kc + s * 8];
    }
    {
      int r = t >> 2, s4 = t & 3;  // 64 rows x 4 granules
      long o = ((long)g * 64 + r) * 256 + kc + s4 * 8;
      *(uint4*)&sBh[r * 40 + s4 * 8] = *(const uint4*)&kvsTh[o];
      *(uint4*)&sBl[r * 40 + s4 * 8] = *(const uint4*)&kvsTl[o];
    }
    __syncthreads();
    bf16x8 af[2], bh[4], bl[4];
    #pragma unroll
    for (int i = 0; i < 2; i++)
      af[i] = *(const bf16x8*)&sA[(wm0 + i * 16 + ll) * 40 + quad * 8];
    #pragma unroll
    for (int j = 0; j < 4; j++) {
      bh[j] = *(const bf16x8*)&sBh[(j * 16 + ll) * 40 + quad * 8];
      bl[j] = *(const bf16x8*)&sBl[(j * 16 + ll) * 40 + quad * 8];
    }
    #pragma unroll
    for (int i = 0; i < 2; i++)
      #pragma unroll
      for (int j = 0; j < 4; j++) {
        acc[i][j] = __builtin_amdgcn_mfma_f32_16x16x32_bf16(af[i], bh[j], acc[i][j], 0, 0, 0);
        acc[i][j] = __builtin_amdgcn_mfma_f32_16x16x32_bf16(af[i], bl[j], acc[i][j], 0, 0, 0);
      }
    __syncthreads();
  }
  // Epilogue: nrm in-register, LDS bounce, coalesced uint4 stores.
  u16* sT = pool;  // [128][72]
  #pragma unroll
  for (int i = 0; i < 2; i++)
    #pragma unroll
    for (int r = 0; r < 4; r++) {
      int lrow = wm0 + i * 16 + quad * 4 + r;
      float nv = nrm[(l0 + lrow) * 16 + h];
      #pragma unroll
      for (int j = 0; j < 4; j++)
        sT[lrow * 72 + j * 16 + ll] = f2bf(acc[i][j][r] * nv);
    }
  __syncthreads();
  for (int u = t; u < 1024; u += 256) {
    int lrow = u >> 3, c8 = (u & 7) * 8;
    *(uint4*)&av[(long)(l0 + lrow) * 1024 + h * 64 + c8] =
        *(const uint4*)&sT[lrow * 72 + c8];
  }
}

extern "C" void kernel_launch(void* const* d_in, const int* in_sizes, int n_in,
                              void* d_out, int out_size, void* d_ws, size_t ws_size,
                              hipStream_t stream) {
  const void* src  = d_in[0];
  const void* posf = d_in[1];
  const void* slpf = d_in[2];
  const void* wv   = d_in[3];
  const void* wp   = d_in[4];
  const void* scl  = d_in[5];
  const void* offs = d_in[6];
  const void* wo   = d_in[7];
  const void* proj = d_in[8];
  const unsigned* probe = (const unsigned*)d_in[5];
  char* ws = (char*)d_ws;
  const size_t KiB = 1024;
  const size_t MiB = 1024 * 1024;

  u16*   wvt   = (u16*)(ws + 0 * MiB);
  u16*   wot   = (u16*)(ws + 2 * MiB);
  u16*   W2    = (u16*)(ws + 4 * MiB);                 // [1024][2048] hi|lo
  float* nrm   = (float*)(ws + 8 * MiB);               // 256 KiB
  u16*   P2    = (u16*)(ws + 8 * MiB + 256 * KiB);     // 64 KiB
  u16*   kvsTh = (u16*)(ws + 8 * MiB + 320 * KiB);     // 512 KiB
  u16*   kvsTl = (u16*)(ws + 8 * MiB + 832 * KiB);     // 512 KiB
  float* posp  = (float*)(ws + 10 * MiB);              // 16 MiB
  float* slpp  = (float*)(ws + 26 * MiB);              // 16 MiB
  u16*   valb  = (u16*)(ws + 42 * MiB);                // 8 MiB (fallback only)
  u16*   av    = valb;                                  // alias
  u16*   vT    = (u16*)(ws + 50 * MiB);                // 8 MiB
  char*  dyn   = ws + 58 * MiB;

  const int KS = 16;
  int G = 1;
  int stacked = 0;
  if (ws_size >= 122 * MiB) { G = 16; stacked = 1; }
  else if (ws_size >= 92 * MiB) { G = 4; stacked = 1; }
  u16* qp  = (u16*)dyn;
  u16* kpT = (u16*)(dyn + 2 * (size_t)G * MiB);
  u16* A2  = (u16*)dyn;                                // 32 MiB, aliases qp+
  u16* srcb = (G == 16) ? kpT : (u16*)dyn;
  float* kvp = (G == 16) ? posp : (float*)(dyn + 4 * (size_t)G * MiB);

  dim3 blk(256);
  transpose_w<<<dim3(16, 16), blk, 0, stream>>>(wv, wvt, probe);
  transpose_w<<<dim3(16, 16), blk, 0, stream>>>(wo, wot, probe);
  transpose_w2<<<dim3(16, 16), blk, 0, stream>>>(wp, W2, probe);
  proj_prep<<<dim3(32), blk, 0, stream>>>(proj, P2, probe);

  if (G == 16) {
    stage3<<<dim3(6144), blk, 0, stream>>>(posf, slpf, src, 0, A2, srcb, probe);
    for (int b = 0; b < 4; b++) {
      long ioff = (long)b * 4096 * 1024;
      gemm_mega<<<dim3(768), blk, 0, stream>>>(A2, W2, posp, srcb, wvt, vT, probe);
      norm_kernel<<<dim3(256), blk, 0, stream>>>(slpp, nrm);
      featurize_mfma<<<dim3(64, 16), blk, 0, stream>>>(
          posp, slpp, P2, scl, offs, qp, kpT, probe, 0);
      kvs_mfma<<<dim3(KS, 16), blk, 0, stream>>>(kpT, vT, kvp, 0);
      kvs_reduce<<<dim3(16 * 64), blk, 0, stream>>>(kvp, kvsTh, kvsTl, 16, KS);
      av_mfma<<<dim3(32, 16), blk, 0, stream>>>(qp, kvsTh, kvsTl, nrm, av, 0);
      if (b < 3) {
        long ioff_n = (long)(b + 1) * 4096 * 1024;
        mega2<<<dim3(6400), blk, 0, stream>>>(av, wot, d_out, ioff,
                                              posf, slpf, src, ioff_n,
                                              A2, srcb, probe);
      } else {
        gemm_gl<<<dim3(32, 8), blk, 0, stream>>>(av, 1024, wot, 1024,
                                                 d_out, ioff, 1024, 0, 2, probe);
      }
    }
  } else {
    for (int b = 0; b < 4; b++) {
      long ioff = (long)b * 4096 * 1024;
      if (stacked) {
        split_hilo<<<dim3(2048), blk, 0, stream>>>(posf, ioff, A2, 0, probe);
        split_hilo<<<dim3(2048), blk, 0, stream>>>(slpf, ioff, A2, 4096, probe);
        gemm_gl<<<dim3(64, 8), blk, 0, stream>>>(A2, 2048, W2, 2048,
                                                 posp, 0, 3072, 1, 1, probe);
      } else {
        split_hilo<<<dim3(2048), blk, 0, stream>>>(posf, ioff, A2, 0, probe);
        gemm_gl<<<dim3(32, 8), blk, 0, stream>>>(A2, 2048, W2, 2048,
                                                 posp, 0, 3072, 1, 1, probe);
        split_hilo<<<dim3(2048), blk, 0, stream>>>(slpf, ioff, A2, 0, probe);
        gemm_gl<<<dim3(32, 8), blk, 0, stream>>>(A2, 2048, W2, 2048,
                                                 slpp, 0, 3072, 1, 1, probe);
      }
      norm_kernel<<<dim3(256), blk, 0, stream>>>(slpp, nrm);
      conv_bf16<<<dim3(2048), blk, 0, stream>>>(src, ioff, srcb, probe);
      gemm_gl<<<dim3(32, 8), blk, 0, stream>>>(srcb, 1024, wvt, 1024,
                                               valb, 0, 1024, 0, 0, probe);
      transpose_v<<<dim3(16, 64), blk, 0, stream>>>(valb, vT);
      for (int hg = 0; hg < 16; hg += G) {
        featurize_mfma<<<dim3(64, G), blk, 0, stream>>>(
            posp, slpp, P2, scl, offs, qp, kpT, probe, hg);
        kvs_mfma<<<dim3(KS, G), blk, 0, stream>>>(kpT, vT, kvp, hg);
        kvs_reduce<<<dim3(G * 64), blk, 0, stream>>>(kvp, kvsTh, kvsTl, G, KS);
        av_mfma<<<dim3(32, G), blk, 0, stream>>>(qp, kvsTh, kvsTl, nrm, av, hg);
      }
      gemm_gl<<<dim3(32, 8), blk, 0, stream>>>(av, 1024, wot, 1024,
                                               d_out, ioff, 1024, 0, 2, probe);
    }
  }
}